// Round 7
// baseline (855.685 us; speedup 1.0000x reference)
//
#include <hip/hip_runtime.h>

// Sizes (fixed for this problem)
#define T_TOK 1024
#define H_DIM 2048
#define E_NUM 32
#define I_DIM 1024
#define IS_DIM 2048

typedef float  f32x4 __attribute__((ext_vector_type(4)));
typedef short  s16x8 __attribute__((ext_vector_type(8)));
typedef unsigned short u16x4 __attribute__((ext_vector_type(4)));
typedef unsigned short u16x8 __attribute__((ext_vector_type(8)));

__device__ __forceinline__ unsigned short f2bf(float f) {
    unsigned u = __builtin_bit_cast(unsigned, f);
    u = (u + 0x7fffu + ((u >> 16) & 1u)) >> 16;
    return (unsigned short)u;
}

// LDS column swizzle: rows are 32 u16 (64 B); XOR col-block (8 u16) with
// row bits so strided row access spreads across banks; 16B-aligned preserved.
__device__ __forceinline__ int swz(int r, int c) {
    return (r << 5) + (c ^ (((r >> 2) & 3) << 3));
}

// ---------------------------------------------------------------------------
// x (fp32) -> bf16, done once; all GEMM A-operands become bf16.
// ---------------------------------------------------------------------------
__global__ __launch_bounds__(256) void cvt_k(
    const float* __restrict__ x, unsigned short* __restrict__ xb)
{
    const int i = (blockIdx.x * 256 + threadIdx.x) * 8;
    f32x4 a = *(const f32x4*)(x + i);
    f32x4 b = *(const f32x4*)(x + i + 4);
    u16x8 h = { f2bf(a[0]), f2bf(a[1]), f2bf(a[2]), f2bf(a[3]),
                f2bf(b[0]), f2bf(b[1]), f2bf(b[2]), f2bf(b[3]) };
    *(u16x8*)(xb + i) = h;
}

// ---------------------------------------------------------------------------
// Routing: 4 tokens per 256-thread block, one wave per token.
// ---------------------------------------------------------------------------
__global__ __launch_bounds__(256) void route_k(
    const float* __restrict__ x, const float* __restrict__ gw,
    const float* __restrict__ bias, int* __restrict__ tidx,
    float* __restrict__ tw)
{
    const int w = threadIdx.x >> 6;
    const int lane = threadIdx.x & 63;
    const int t = blockIdx.x * 4 + w;
    __shared__ float xs[4][H_DIM];
    __shared__ float sfc[4][E_NUM];
    __shared__ float sc[4][E_NUM];

    for (int i = threadIdx.x; i < 4 * (H_DIM / 4); i += 256) {
        int tt = i >> 9;
        int c = i & 511;
        *(f32x4*)&xs[tt][c * 4] =
            *(const f32x4*)(x + (size_t)(blockIdx.x * 4 + tt) * H_DIM + c * 4);
    }
    __syncthreads();

    const int eq = (lane & 7) * 4;
    const int hs = lane >> 3;
    f32x4 acc = {0.f, 0.f, 0.f, 0.f};
    #pragma unroll 4
    for (int h = hs; h < H_DIM; h += 8) {
        float xv = xs[w][h];
        f32x4 gv = *(const f32x4*)(gw + (size_t)h * E_NUM + eq);
        acc += gv * xv;
    }
    #pragma unroll
    for (int m = 8; m < 64; m <<= 1) {
        acc[0] += __shfl_xor(acc[0], m);
        acc[1] += __shfl_xor(acc[1], m);
        acc[2] += __shfl_xor(acc[2], m);
        acc[3] += __shfl_xor(acc[3], m);
    }
    if (lane < 8) {
        #pragma unroll
        for (int j = 0; j < 4; ++j) {
            float s = 1.f / (1.f + expf(-acc[j]));
            sc[w][eq + j] = s;
            sfc[w][eq + j] = s + bias[eq + j];
        }
    }
    __syncthreads();

    if (lane == 0) {
        float gs[4];
        for (int gg = 0; gg < 4; ++gg) {
            float m1 = -1e30f, m2 = -1e30f;
            for (int j = 0; j < 8; ++j) {
                float v = sfc[w][gg * 8 + j];
                if (v > m1) { m2 = m1; m1 = v; }
                else if (v > m2) { m2 = v; }
            }
            gs[gg] = m1 + m2;
        }
        int g1 = 0;
        for (int gg = 1; gg < 4; ++gg) if (gs[gg] > gs[g1]) g1 = gg;
        int g2 = (g1 == 0) ? 1 : 0;
        for (int gg = 0; gg < 4; ++gg)
            if (gg != g1 && gs[gg] > gs[g2]) g2 = gg;

        unsigned allow = (0xFFu << (g1 * 8)) | (0xFFu << (g2 * 8));
        unsigned taken = 0u;
        int   isel[8];
        float wsel[8];
        float wsum = 0.f;
        for (int k = 0; k < 8; ++k) {
            int best = 0; float bv = -1e30f;
            for (int e2 = 0; e2 < 32; ++e2) {
                if (((allow >> e2) & 1u) && !((taken >> e2) & 1u)) {
                    float v = sfc[w][e2];
                    if (v > bv) { bv = v; best = e2; }
                }
            }
            taken |= 1u << best;
            isel[k] = best;
            wsel[k] = sc[w][best];
            wsum += sc[w][best];
        }
        const float f = 2.5f / wsum;
        for (int k = 0; k < 8; ++k) {
            tidx[t * 8 + k] = isel[k];
            tw[t * 8 + k] = wsel[k] * f;
        }
    }
}

// ---------------------------------------------------------------------------
// Build per-expert token lists (ascending token id). One wave per expert.
// ---------------------------------------------------------------------------
__global__ __launch_bounds__(64) void build_k(
    const int* __restrict__ tidx, const float* __restrict__ tw,
    int* __restrict__ ltok, float* __restrict__ lw, int* __restrict__ counts)
{
    const int e = blockIdx.x;
    const int lane = threadIdx.x;
    int cnt = 0;
    for (int t0 = 0; t0 < T_TOK; t0 += 64) {
        const int t = t0 + lane;
        int sel = 0; float w = 0.f;
        #pragma unroll
        for (int k = 0; k < 8; ++k) {
            if (tidx[t * 8 + k] == e) { sel = 1; w = tw[t * 8 + k]; }
        }
        unsigned long long m = __ballot(sel);
        int pos = __popcll(m & ((1ull << lane) - 1ull));
        if (sel) {
            ltok[e * T_TOK + cnt + pos] = t;
            lw[e * T_TOK + cnt + pos] = w;
        }
        cnt += __popcll(m);
    }
    if (lane == 0) counts[e] = cnt;
}

__global__ void prefix_k(const int* __restrict__ counts, int* __restrict__ offsets)
{
    if (threadIdx.x == 0) {
        int off = 0;
        for (int e = 0; e < E_NUM; ++e) { offsets[e] = off; off += counts[e]; }
    }
}

// ---------------------------------------------------------------------------
// GEMM: BMx64 tile, BK=32, 256 threads (4 waves, 2Mx2N, wave tile WRx32),
// double-buffered swizzled LDS, depth-2 register pipeline, bf16 A always.
// GATHER: A rows via ltok (routed gate/up). EXPERT: blockIdx.z = expert.
// ---------------------------------------------------------------------------
template<int DUAL, int EXPERT, int GATHER, int ATOMIC, int BM>
__global__ __launch_bounds__(256, 4) void gemm_k(
    const unsigned short* __restrict__ A, const float* __restrict__ B1g,
    const float* __restrict__ B2g, void* __restrict__ outv,
    const int* __restrict__ counts, const int* __restrict__ offsets,
    const int* __restrict__ ltok, const float* __restrict__ lw,
    int M, int N, int K)
{
    constexpr int WR  = BM / 2;        // rows per M-wave
    constexpr int FM  = WR / 16;       // A frags per wave
    constexpr int TPR = 256 / BM;      // threads per A row (2 or 4)
    constexpr int KSP = 32 / TPR;      // k elems per thread (16 or 8)
    constexpr int NB  = KSP / 8;       // u16x8 ops per A row chunk

    const int e = blockIdx.z;
    const int Mloc = EXPERT ? counts[e] : M;
    const int col0 = blockIdx.y * 64;
    const int rb = EXPERT ? offsets[e] : 0;

    const float* B1 = B1g;
    const float* B2 = B2g;
    if (EXPERT) {
        size_t eo = (size_t)e * K * N;
        B1 += eo;
        if (DUAL) B2 += eo;
    }

    __shared__ unsigned short lA[2][BM * 32];
    __shared__ unsigned short lB[2][DUAL + 1][64 * 32];

    const int tid = threadIdx.x;
    const int lane = tid & 63;
    const int wv = tid >> 6;
    const int wm = wv >> 1;            // 0..1
    const int wn = wv & 1;             // 0..1

    const int arow = tid / TPR;
    const int akb  = (tid % TPR) * KSP;

    // ---- B staging: 4k x 4n micro-tile per thread ----
    const bool doB = tid < (DUAL ? 256 : 128);
    const int bmat = DUAL ? (tid >> 7) : 0;
    const int t7 = tid & 127;
    const int nq = t7 & 15;
    const int kq = t7 >> 4;
    const float* bp = (bmat ? B2 : B1) + (size_t)(4 * kq) * N + col0 + nq * 4;

    f32x4 acc1[FM][2], acc2[FM][2];
    u16x8 pbaX[NB], pbaY[NB];
    f32x4 pbX[4], pbY[4];
    const unsigned short* apb = nullptr;

    auto loadT = [&](int k0, u16x8 (&pba)[NB], f32x4 (&pb)[4]) {
        #pragma unroll
        for (int i = 0; i < NB; ++i)
            pba[i] = *(const u16x8*)(apb + k0 + i * 8);
        if (doB) {
            #pragma unroll
            for (int j = 0; j < 4; ++j)
                pb[j] = *(const f32x4*)(bp + (size_t)(k0 + j) * N);
        }
    };

    auto storeT = [&](int p, u16x8 (&pba)[NB], f32x4 (&pb)[4]) {
        #pragma unroll
        for (int i = 0; i < NB; ++i)
            *(u16x8*)&lA[p][swz(arow, akb + i * 8)] = pba[i];
        if (doB) {
            #pragma unroll
            for (int j2 = 0; j2 < 4; ++j2) {
                u16x4 h = { f2bf(pb[0][j2]), f2bf(pb[1][j2]),
                            f2bf(pb[2][j2]), f2bf(pb[3][j2]) };
                *(u16x4*)&lB[p][bmat][swz(nq * 4 + j2, kq * 4)] = h;
            }
        }
    };

    auto compute = [&](int p) {
        const int koff = (lane >> 4) * 8;
        s16x8 af[FM], b1f[2], b2f[2];
        #pragma unroll
        for (int fm = 0; fm < FM; ++fm)
            af[fm] = *(const s16x8*)&lA[p][swz(wm * WR + fm * 16 + (lane & 15), koff)];
        #pragma unroll
        for (int fn = 0; fn < 2; ++fn) {
            b1f[fn] = *(const s16x8*)&lB[p][0][swz(wn * 32 + fn * 16 + (lane & 15), koff)];
            if (DUAL)
                b2f[fn] = *(const s16x8*)&lB[p][1][swz(wn * 32 + fn * 16 + (lane & 15), koff)];
        }
        #pragma unroll
        for (int fm = 0; fm < FM; ++fm)
            #pragma unroll
            for (int fn = 0; fn < 2; ++fn) {
                acc1[fm][fn] = __builtin_amdgcn_mfma_f32_16x16x32_bf16(
                    af[fm], b1f[fn], acc1[fm][fn], 0, 0, 0);
                if (DUAL)
                    acc2[fm][fn] = __builtin_amdgcn_mfma_f32_16x16x32_bf16(
                        af[fm], b2f[fn], acc2[fm][fn], 0, 0, 0);
            }
    };

    const int nk = K >> 5;             // 32 or 64, even

    for (int row0 = blockIdx.x * BM; row0 < Mloc; row0 += gridDim.x * BM) {
        {
            int rr = row0 + arow;
            if (rr >= Mloc) rr = Mloc - 1;
            int grow = GATHER ? ltok[e * T_TOK + rr] : (rb + rr);
            apb = A + (size_t)grow * K + akb;
        }
        #pragma unroll
        for (int a = 0; a < FM; ++a)
            #pragma unroll
            for (int b = 0; b < 2; ++b) {
                acc1[a][b] = f32x4{0.f, 0.f, 0.f, 0.f};
                acc2[a][b] = f32x4{0.f, 0.f, 0.f, 0.f};
            }

        loadT(0, pbaX, pbX);
        loadT(32, pbaY, pbY);
        __syncthreads();               // prior m-tile done with LDS
        storeT(0, pbaX, pbX);
        __syncthreads();

        for (int kt = 0; kt < nk; kt += 2) {
            if (kt + 2 < nk) loadT((kt + 2) << 5, pbaX, pbX);
            compute(0);
            storeT(1, pbaY, pbY);
            __syncthreads();
            if (kt + 3 < nk) loadT((kt + 3) << 5, pbaY, pbY);
            compute(1);
            if (kt + 2 < nk) {
                storeT(0, pbaX, pbX);
                __syncthreads();
            }
        }

        // ---- epilogue ----
        const int fr = (lane >> 4) << 2;
        const int fc = lane & 15;
        if (DUAL) {
            unsigned short* outp = (unsigned short*)outv;
            #pragma unroll
            for (int fm = 0; fm < FM; ++fm)
                #pragma unroll
                for (int fn = 0; fn < 2; ++fn)
                    #pragma unroll
                    for (int j = 0; j < 4; ++j) {
                        int r = wm * WR + fm * 16 + fr + j;
                        if (row0 + r < Mloc) {
                            int cc = col0 + wn * 32 + fn * 16 + fc;
                            float gv = acc1[fm][fn][j];
                            float uv = acc2[fm][fn][j];
                            float a = gv / (1.f + expf(-gv)) * uv;
                            outp[(size_t)(rb + row0 + r) * N + cc] = f2bf(a);
                        }
                    }
        } else if (ATOMIC) {
            float* outp = (float*)outv;
            #pragma unroll
            for (int fm = 0; fm < FM; ++fm)
                #pragma unroll
                for (int fn = 0; fn < 2; ++fn)
                    #pragma unroll
                    for (int j = 0; j < 4; ++j) {
                        int r = wm * WR + fm * 16 + fr + j;
                        if (row0 + r < Mloc) {
                            int tok = ltok[e * T_TOK + row0 + r];
                            float wr = lw[e * T_TOK + row0 + r];
                            int cc = col0 + wn * 32 + fn * 16 + fc;
                            atomicAdd(outp + (size_t)tok * N + cc, acc1[fm][fn][j] * wr);
                        }
                    }
        } else {
            float* outp = (float*)outv;
            #pragma unroll
            for (int fm = 0; fm < FM; ++fm)
                #pragma unroll
                for (int fn = 0; fn < 2; ++fn)
                    #pragma unroll
                    for (int j = 0; j < 4; ++j) {
                        int r = wm * WR + fm * 16 + fr + j;
                        if (row0 + r < Mloc) {
                            int cc = col0 + wn * 32 + fn * 16 + fc;
                            outp[(size_t)(row0 + r) * N + cc] = acc1[fm][fn][j];
                        }
                    }
        }
    }
}

// ---------------------------------------------------------------------------
extern "C" void kernel_launch(void* const* d_in, const int* in_sizes, int n_in,
                              void* d_out, int out_size, void* d_ws, size_t ws_size,
                              hipStream_t stream) {
    const float* x       = (const float*)d_in[0];
    const float* gate_w  = (const float*)d_in[1];
    const float* bias    = (const float*)d_in[2];
    const float* w_gate  = (const float*)d_in[3];
    const float* w_up    = (const float*)d_in[4];
    const float* w_down  = (const float*)d_in[5];
    const float* sw_gate = (const float*)d_in[6];
    const float* sw_up   = (const float*)d_in[7];
    const float* sw_down = (const float*)d_in[8];
    float* out = (float*)d_out;

    char* ws = (char*)d_ws;
    int*   topk_idx = (int*)ws;                                   // 32 KB
    float* topk_w   = (float*)(ws + 32768);                       // 32 KB
    int*   counts   = (int*)(ws + 65536);                         // 128 B
    int*   offsets  = (int*)(ws + 65536 + 128);                   // 128 B
    int*   ltok     = (int*)(ws + 65536 + 256);                   // 128 KB
    float* lw       = (float*)(ws + 65536 + 256 + 131072);        // 128 KB
    unsigned short* act_s = (unsigned short*)(ws + 65536 + 256 + 262144);   // 4 MB
    unsigned short* act_r = act_s + (size_t)T_TOK * IS_DIM;                 // 16 MB
    unsigned short* xbf   = act_r + (size_t)T_TOK * 8 * I_DIM;              // 4 MB

    cvt_k<<<T_TOK * H_DIM / 2048, 256, 0, stream>>>(x, xbf);
    route_k<<<T_TOK / 4, 256, 0, stream>>>(x, gate_w, bias, topk_idx, topk_w);
    build_k<<<E_NUM, 64, 0, stream>>>(topk_idx, topk_w, ltok, lw, counts);
    prefix_k<<<1, 64, 0, stream>>>(counts, offsets);

    // shared gate/up -> act_s (bf16): BM=64, 512 blocks
    gemm_k<1,0,0,0,64><<<dim3(16, 32, 1), 256, 0, stream>>>(
        xbf, sw_gate, sw_up, act_s, nullptr, nullptr, nullptr, nullptr,
        T_TOK, IS_DIM, H_DIM);
    // routed gate/up -> act_r (bf16): BM=128, 1024 blocks (4/CU)
    gemm_k<1,1,1,0,128><<<dim3(2, 16, 32), 256, 0, stream>>>(
        xbf, w_gate, w_up, act_r, counts, offsets, ltok, lw,
        T_TOK, I_DIM, H_DIM);
    // shared down -> out (plain store, initializes out): BM=64, 512 blocks
    gemm_k<0,0,0,0,64><<<dim3(16, 32, 1), 256, 0, stream>>>(
        act_s, sw_down, nullptr, out, nullptr, nullptr, nullptr, nullptr,
        T_TOK, H_DIM, IS_DIM);
    // routed down -> out (scaled atomicAdd): BM=128, 2048 blocks
    gemm_k<0,1,0,1,128><<<dim3(2, 32, 32), 256, 0, stream>>>(
        act_r, w_down, nullptr, out, counts, offsets, ltok, lw,
        T_TOK, H_DIM, I_DIM);
}

// Round 8
// 783.189 us; speedup vs baseline: 1.0926x; 1.0926x over previous
//
#include <hip/hip_runtime.h>

// Sizes (fixed for this problem)
#define T_TOK 1024
#define H_DIM 2048
#define E_NUM 32
#define I_DIM 1024
#define IS_DIM 2048

typedef float  f32x4 __attribute__((ext_vector_type(4)));
typedef short  s16x8 __attribute__((ext_vector_type(8)));
typedef unsigned short u16x4 __attribute__((ext_vector_type(4)));
typedef unsigned short u16x8 __attribute__((ext_vector_type(8)));

__device__ __forceinline__ unsigned short f2bf(float f) {
    unsigned u = __builtin_bit_cast(unsigned, f);
    u = (u + 0x7fffu + ((u >> 16) & 1u)) >> 16;
    return (unsigned short)u;
}

// LDS column swizzle: rows are 32 u16 (64 B); XOR col-block (8 u16) with
// row bits so strided row access spreads across banks; 16B alignment kept.
__device__ __forceinline__ int swz(int r, int c) {
    return (r << 5) + (c ^ (((r >> 2) & 3) << 3));
}

// ---------------------------------------------------------------------------
// x (fp32) -> bf16 once; all GEMM A-operands are bf16.
// ---------------------------------------------------------------------------
__global__ __launch_bounds__(256) void cvt_k(
    const float* __restrict__ x, unsigned short* __restrict__ xb)
{
    const int i = (blockIdx.x * 256 + threadIdx.x) * 8;
    f32x4 a = *(const f32x4*)(x + i);
    f32x4 b = *(const f32x4*)(x + i + 4);
    u16x8 h = { f2bf(a[0]), f2bf(a[1]), f2bf(a[2]), f2bf(a[3]),
                f2bf(b[0]), f2bf(b[1]), f2bf(b[2]), f2bf(b[3]) };
    *(u16x8*)(xb + i) = h;
}

// ---------------------------------------------------------------------------
// Routing: 4 tokens per 256-thread block, one wave per token.
// ---------------------------------------------------------------------------
__global__ __launch_bounds__(256) void route_k(
    const float* __restrict__ x, const float* __restrict__ gw,
    const float* __restrict__ bias, int* __restrict__ tidx,
    float* __restrict__ tw)
{
    const int w = threadIdx.x >> 6;
    const int lane = threadIdx.x & 63;
    const int t = blockIdx.x * 4 + w;
    __shared__ float xs[4][H_DIM];
    __shared__ float sfc[4][E_NUM];
    __shared__ float sc[4][E_NUM];

    for (int i = threadIdx.x; i < 4 * (H_DIM / 4); i += 256) {
        int tt = i >> 9;
        int c = i & 511;
        *(f32x4*)&xs[tt][c * 4] =
            *(const f32x4*)(x + (size_t)(blockIdx.x * 4 + tt) * H_DIM + c * 4);
    }
    __syncthreads();

    const int eq = (lane & 7) * 4;
    const int hs = lane >> 3;
    f32x4 acc = {0.f, 0.f, 0.f, 0.f};
    #pragma unroll 4
    for (int h = hs; h < H_DIM; h += 8) {
        float xv = xs[w][h];
        f32x4 gv = *(const f32x4*)(gw + (size_t)h * E_NUM + eq);
        acc += gv * xv;
    }
    #pragma unroll
    for (int m = 8; m < 64; m <<= 1) {
        acc[0] += __shfl_xor(acc[0], m);
        acc[1] += __shfl_xor(acc[1], m);
        acc[2] += __shfl_xor(acc[2], m);
        acc[3] += __shfl_xor(acc[3], m);
    }
    if (lane < 8) {
        #pragma unroll
        for (int j = 0; j < 4; ++j) {
            float s = 1.f / (1.f + expf(-acc[j]));
            sc[w][eq + j] = s;
            sfc[w][eq + j] = s + bias[eq + j];
        }
    }
    __syncthreads();

    if (lane == 0) {
        float gs[4];
        for (int gg = 0; gg < 4; ++gg) {
            float m1 = -1e30f, m2 = -1e30f;
            for (int j = 0; j < 8; ++j) {
                float v = sfc[w][gg * 8 + j];
                if (v > m1) { m2 = m1; m1 = v; }
                else if (v > m2) { m2 = v; }
            }
            gs[gg] = m1 + m2;
        }
        int g1 = 0;
        for (int gg = 1; gg < 4; ++gg) if (gs[gg] > gs[g1]) g1 = gg;
        int g2 = (g1 == 0) ? 1 : 0;
        for (int gg = 0; gg < 4; ++gg)
            if (gg != g1 && gs[gg] > gs[g2]) g2 = gg;

        unsigned allow = (0xFFu << (g1 * 8)) | (0xFFu << (g2 * 8));
        unsigned taken = 0u;
        int   isel[8];
        float wsel[8];
        float wsum = 0.f;
        for (int k = 0; k < 8; ++k) {
            int best = 0; float bv = -1e30f;
            for (int e2 = 0; e2 < 32; ++e2) {
                if (((allow >> e2) & 1u) && !((taken >> e2) & 1u)) {
                    float v = sfc[w][e2];
                    if (v > bv) { bv = v; best = e2; }
                }
            }
            taken |= 1u << best;
            isel[k] = best;
            wsel[k] = sc[w][best];
            wsum += sc[w][best];
        }
        const float f = 2.5f / wsum;
        for (int k = 0; k < 8; ++k) {
            tidx[t * 8 + k] = isel[k];
            tw[t * 8 + k] = wsel[k] * f;
        }
    }
}

// ---------------------------------------------------------------------------
// Build per-expert token lists (ascending token id). One wave per expert.
// ---------------------------------------------------------------------------
__global__ __launch_bounds__(64) void build_k(
    const int* __restrict__ tidx, const float* __restrict__ tw,
    int* __restrict__ ltok, float* __restrict__ lw, int* __restrict__ counts)
{
    const int e = blockIdx.x;
    const int lane = threadIdx.x;
    int cnt = 0;
    for (int t0 = 0; t0 < T_TOK; t0 += 64) {
        const int t = t0 + lane;
        int sel = 0; float w = 0.f;
        #pragma unroll
        for (int k = 0; k < 8; ++k) {
            if (tidx[t * 8 + k] == e) { sel = 1; w = tw[t * 8 + k]; }
        }
        unsigned long long m = __ballot(sel);
        int pos = __popcll(m & ((1ull << lane) - 1ull));
        if (sel) {
            ltok[e * T_TOK + cnt + pos] = t;
            lw[e * T_TOK + cnt + pos] = w;
        }
        cnt += __popcll(m);
    }
    if (lane == 0) counts[e] = cnt;
}

__global__ void prefix_k(const int* __restrict__ counts, int* __restrict__ offsets)
{
    if (threadIdx.x == 0) {
        int off = 0;
        for (int e = 0; e < E_NUM; ++e) { offsets[e] = off; off += counts[e]; }
    }
}

// ---------------------------------------------------------------------------
// GEMM: 128x32 tile, BK=32, 256 threads (4 waves, each wave one 32x32 M-strip),
// double-buffered swizzled LDS, depth-2 register pipeline, in-block m-loop
// (grid.x=1 for routed => each weight panel fetched exactly once from HBM).
// DUAL: gate+up fused w/ SiLU; GATHER: A rows via ltok; ATOMIC: scaled add.
// ---------------------------------------------------------------------------
template<int DUAL, int EXPERT, int GATHER, int ATOMIC>
__global__ __launch_bounds__(256) void gemm_k(
    const unsigned short* __restrict__ A, const float* __restrict__ B1g,
    const float* __restrict__ B2g, void* __restrict__ outv,
    const int* __restrict__ counts, const int* __restrict__ offsets,
    const int* __restrict__ ltok, const float* __restrict__ lw,
    int M, int N, int K)
{
    constexpr int BM = 128;
    constexpr int WR = 32;             // rows per wave strip
    constexpr int FM = 2;              // 16-row frags per wave
    constexpr int NB = 2;              // u16x8 A-chunks per thread (KSP=16)

    const int e = blockIdx.z;
    const int Mloc = EXPERT ? counts[e] : M;
    const int col0 = blockIdx.y * 32;
    const int rb = EXPERT ? offsets[e] : 0;

    const float* B1 = B1g;
    const float* B2 = B2g;
    if (EXPERT) {
        size_t eo = (size_t)e * K * N;
        B1 += eo;
        if (DUAL) B2 += eo;
    }

    __shared__ unsigned short lA[2][BM * 32];
    __shared__ unsigned short lB[2][DUAL + 1][32 * 32];

    const int tid = threadIdx.x;
    const int lane = tid & 63;
    const int wv = tid >> 6;           // 0..3 = M strip

    const int arow = tid >> 1;         // 0..127
    const int akb  = (tid & 1) * 16;   // k half

    // ---- B staging: 64 threads per matrix, 4k x 4n micro-tile each ----
    const bool doB = tid < (DUAL ? 128 : 64);
    const int bmat = DUAL ? (tid >> 6) : 0;
    const int t6 = tid & 63;
    const int nq = t6 & 7;             // n-quad 0..7
    const int kq = t6 >> 3;            // k-quad 0..7
    const float* bp = (bmat ? B2 : B1) + (size_t)(4 * kq) * N + col0 + nq * 4;

    f32x4 acc1[FM][2], acc2[FM][2];
    u16x8 pbaX[NB], pbaY[NB];
    f32x4 pbX[4], pbY[4];
    const unsigned short* apb = nullptr;

    auto loadT = [&](int k0, u16x8 (&pba)[NB], f32x4 (&pb)[4]) {
        #pragma unroll
        for (int i = 0; i < NB; ++i)
            pba[i] = *(const u16x8*)(apb + k0 + i * 8);
        if (doB) {
            #pragma unroll
            for (int j = 0; j < 4; ++j)
                pb[j] = *(const f32x4*)(bp + (size_t)(k0 + j) * N);
        }
    };

    auto storeT = [&](int p, u16x8 (&pba)[NB], f32x4 (&pb)[4]) {
        #pragma unroll
        for (int i = 0; i < NB; ++i)
            *(u16x8*)&lA[p][swz(arow, akb + i * 8)] = pba[i];
        if (doB) {
            #pragma unroll
            for (int j2 = 0; j2 < 4; ++j2) {
                u16x4 h = { f2bf(pb[0][j2]), f2bf(pb[1][j2]),
                            f2bf(pb[2][j2]), f2bf(pb[3][j2]) };
                *(u16x4*)&lB[p][bmat][swz(nq * 4 + j2, kq * 4)] = h;
            }
        }
    };

    auto compute = [&](int p) {
        const int koff = (lane >> 4) * 8;
        s16x8 af[FM], b1f[2], b2f[2];
        #pragma unroll
        for (int fm = 0; fm < FM; ++fm)
            af[fm] = *(const s16x8*)&lA[p][swz(wv * WR + fm * 16 + (lane & 15), koff)];
        #pragma unroll
        for (int fn = 0; fn < 2; ++fn) {
            b1f[fn] = *(const s16x8*)&lB[p][0][swz(fn * 16 + (lane & 15), koff)];
            if (DUAL)
                b2f[fn] = *(const s16x8*)&lB[p][1][swz(fn * 16 + (lane & 15), koff)];
        }
        #pragma unroll
        for (int fm = 0; fm < FM; ++fm)
            #pragma unroll
            for (int fn = 0; fn < 2; ++fn) {
                acc1[fm][fn] = __builtin_amdgcn_mfma_f32_16x16x32_bf16(
                    af[fm], b1f[fn], acc1[fm][fn], 0, 0, 0);
                if (DUAL)
                    acc2[fm][fn] = __builtin_amdgcn_mfma_f32_16x16x32_bf16(
                        af[fm], b2f[fn], acc2[fm][fn], 0, 0, 0);
            }
    };

    const int nk = K >> 5;             // 32 or 64, even

    for (int row0 = blockIdx.x * BM; row0 < Mloc; row0 += gridDim.x * BM) {
        {
            int rr = row0 + arow;
            if (rr >= Mloc) rr = Mloc - 1;
            int grow = GATHER ? ltok[e * T_TOK + rr] : (rb + rr);
            apb = A + (size_t)grow * K + akb;
        }
        #pragma unroll
        for (int a = 0; a < FM; ++a)
            #pragma unroll
            for (int b = 0; b < 2; ++b) {
                acc1[a][b] = f32x4{0.f, 0.f, 0.f, 0.f};
                acc2[a][b] = f32x4{0.f, 0.f, 0.f, 0.f};
            }

        loadT(0, pbaX, pbX);
        loadT(32, pbaY, pbY);
        __syncthreads();               // prior m-tile done with LDS
        storeT(0, pbaX, pbX);
        __syncthreads();

        for (int kt = 0; kt < nk; kt += 2) {
            if (kt + 2 < nk) loadT((kt + 2) << 5, pbaX, pbX);
            compute(0);
            storeT(1, pbaY, pbY);      // counted vmcnt: newer loads in flight
            __syncthreads();
            if (kt + 3 < nk) loadT((kt + 3) << 5, pbaY, pbY);
            compute(1);
            if (kt + 2 < nk) {
                storeT(0, pbaX, pbX);
                __syncthreads();
            }
        }

        // ---- epilogue ----
        const int fr = (lane >> 4) << 2;
        const int fc = lane & 15;
        if (DUAL) {
            unsigned short* outp = (unsigned short*)outv;
            #pragma unroll
            for (int fm = 0; fm < FM; ++fm)
                #pragma unroll
                for (int fn = 0; fn < 2; ++fn)
                    #pragma unroll
                    for (int j = 0; j < 4; ++j) {
                        int r = wv * WR + fm * 16 + fr + j;
                        if (row0 + r < Mloc) {
                            int cc = col0 + fn * 16 + fc;
                            float gv = acc1[fm][fn][j];
                            float uv = acc2[fm][fn][j];
                            float a = gv / (1.f + expf(-gv)) * uv;
                            outp[(size_t)(rb + row0 + r) * N + cc] = f2bf(a);
                        }
                    }
        } else if (ATOMIC) {
            float* outp = (float*)outv;
            #pragma unroll
            for (int fm = 0; fm < FM; ++fm)
                #pragma unroll
                for (int fn = 0; fn < 2; ++fn)
                    #pragma unroll
                    for (int j = 0; j < 4; ++j) {
                        int r = wv * WR + fm * 16 + fr + j;
                        if (row0 + r < Mloc) {
                            int tok = ltok[e * T_TOK + row0 + r];
                            float wr = lw[e * T_TOK + row0 + r];
                            int cc = col0 + fn * 16 + fc;
                            atomicAdd(outp + (size_t)tok * N + cc, acc1[fm][fn][j] * wr);
                        }
                    }
        } else {
            float* outp = (float*)outv;
            #pragma unroll
            for (int fm = 0; fm < FM; ++fm)
                #pragma unroll
                for (int fn = 0; fn < 2; ++fn)
                    #pragma unroll
                    for (int j = 0; j < 4; ++j) {
                        int r = wv * WR + fm * 16 + fr + j;
                        if (row0 + r < Mloc) {
                            int cc = col0 + fn * 16 + fc;
                            outp[(size_t)(row0 + r) * N + cc] = acc1[fm][fn][j];
                        }
                    }
        }
    }
}

// ---------------------------------------------------------------------------
extern "C" void kernel_launch(void* const* d_in, const int* in_sizes, int n_in,
                              void* d_out, int out_size, void* d_ws, size_t ws_size,
                              hipStream_t stream) {
    const float* x       = (const float*)d_in[0];
    const float* gate_w  = (const float*)d_in[1];
    const float* bias    = (const float*)d_in[2];
    const float* w_gate  = (const float*)d_in[3];
    const float* w_up    = (const float*)d_in[4];
    const float* w_down  = (const float*)d_in[5];
    const float* sw_gate = (const float*)d_in[6];
    const float* sw_up   = (const float*)d_in[7];
    const float* sw_down = (const float*)d_in[8];
    float* out = (float*)d_out;

    char* ws = (char*)d_ws;
    int*   topk_idx = (int*)ws;                                   // 32 KB
    float* topk_w   = (float*)(ws + 32768);                       // 32 KB
    int*   counts   = (int*)(ws + 65536);                         // 128 B
    int*   offsets  = (int*)(ws + 65536 + 128);                   // 128 B
    int*   ltok     = (int*)(ws + 65536 + 256);                   // 128 KB
    float* lw       = (float*)(ws + 65536 + 256 + 131072);        // 128 KB
    unsigned short* act_s = (unsigned short*)(ws + 65536 + 256 + 262144);   // 4 MB
    unsigned short* act_r = act_s + (size_t)T_TOK * IS_DIM;                 // 16 MB
    unsigned short* xbf   = act_r + (size_t)T_TOK * 8 * I_DIM;              // 4 MB

    cvt_k<<<T_TOK * H_DIM / 2048, 256, 0, stream>>>(x, xbf);
    route_k<<<T_TOK / 4, 256, 0, stream>>>(x, gate_w, bias, topk_idx, topk_w);
    build_k<<<E_NUM, 64, 0, stream>>>(topk_idx, topk_w, ltok, lw, counts);
    prefix_k<<<1, 64, 0, stream>>>(counts, offsets);

    // shared gate/up -> act_s (bf16): sw weights are L3-resident -> x-split ok
    gemm_k<1,0,0,0><<<dim3(8, IS_DIM / 32, 1), 256, 0, stream>>>(
        xbf, sw_gate, sw_up, act_s, nullptr, nullptr, nullptr, nullptr,
        T_TOK, IS_DIM, H_DIM);
    // routed gate/up -> act_r (bf16): weights once (grid.x=1), 1024 blocks
    gemm_k<1,1,1,0><<<dim3(1, I_DIM / 32, E_NUM), 256, 0, stream>>>(
        xbf, w_gate, w_up, act_r, counts, offsets, ltok, lw,
        T_TOK, I_DIM, H_DIM);
    // shared down -> out (plain store, initializes out)
    gemm_k<0,0,0,0><<<dim3(8, H_DIM / 32, 1), 256, 0, stream>>>(
        act_s, sw_down, nullptr, out, nullptr, nullptr, nullptr, nullptr,
        T_TOK, H_DIM, IS_DIM);
    // routed down -> out (scaled atomicAdd): weights once, 2048 blocks
    gemm_k<0,1,0,1><<<dim3(1, H_DIM / 32, E_NUM), 256, 0, stream>>>(
        act_r, w_down, nullptr, out, counts, offsets, ltok, lw,
        T_TOK, H_DIM, I_DIM);
}